// Round 6
// baseline (384.364 us; speedup 1.0000x reference)
//
#include <hip/hip_runtime.h>
#include <math.h>

#define N_NODES 50000
#define N_PAD   50048
#define N_EDGES 800000
#define FEAT 128
#define K2 256
#define N_GRAPHS 512
#define N_CLASSES 10
#define BCAP 64         // bucket capacity (deg ~ Poisson(16); P(>64) ~ 0)
#define RANGE_SZ 6250   // 50000 / 8 XCD dst ranges
#define FILL_CHUNK 3125 // 800000 / 256 chunks
#define TROWS 32        // rows per sage_layer block
#define LROW 136        // LDS agg row stride in shorts (+8 pad -> 2-way banks)

typedef __attribute__((ext_vector_type(8))) short short8;
typedef __attribute__((ext_vector_type(4))) float floatx4;

// ---------- bf16 helpers ----------
__device__ __forceinline__ float bflo(unsigned u) { return __uint_as_float(u << 16); }
__device__ __forceinline__ float bfhi(unsigned u) { return __uint_as_float(u & 0xffff0000u); }
__device__ __forceinline__ unsigned short f2bf(float f) {
    unsigned u = __float_as_uint(f);
    u = (u + 0x7fffu + ((u >> 16) & 1u)) >> 16;   // RNE
    return (unsigned short)u;
}
__device__ __forceinline__ unsigned pack2(float a, float b) {
    return (unsigned)f2bf(a) | ((unsigned)f2bf(b) << 16);
}

// ---------- fused graph setup + conversions ----------
// blocks [0,2048): XCD-local dst-range bucket fill (blockIdx&7 ~ XCD id;
//   each XCD's 800 KB ushort bucket slice stays L2-resident so writes merge).
// blocks [2048, 2048+6250): x -> bf16 dense h0
// next 384: weight transpose+concat -> bf16 Wt[layer][n][k]
// last 3: goffs binary search
__global__ __launch_bounds__(256) void fill_setup(
    const int* __restrict__ src, const int* __restrict__ dst,
    int* __restrict__ cnt, unsigned short* __restrict__ bucket,
    const float* __restrict__ x, unsigned short* __restrict__ h0,
    const float* __restrict__ wl1, const float* __restrict__ wr1,
    const float* __restrict__ wl23, const float* __restrict__ wr23,
    unsigned short* __restrict__ wt,
    const int* __restrict__ batch, int* __restrict__ goffs) {
    int b = blockIdx.x;
    if (b < 2048) {
        int xcd = b & 7;
        int chunk = b >> 3;           // 0..255
        int lo = xcd * RANGE_SZ, hi = lo + RANGE_SZ;
        int e0 = chunk * FILL_CHUNK;
        int e1 = e0 + FILL_CHUNK;
        for (int e = e0 + threadIdx.x; e < e1; e += 256) {
            int d = dst[e];
            if (d >= lo && d < hi) {
                int p = atomicAdd(&cnt[d], 1);
                if (p < BCAP) bucket[(size_t)d * BCAP + p] = (unsigned short)src[e];
            }
        }
    } else if (b < 2048 + 6250) {
        int idx = (b - 2048) * 256 + threadIdx.x;   // n*32 + f4
        if (idx < N_NODES * 32) {
            int n = idx >> 5, f4 = idx & 31;
            float4 v = ((const float4*)(x + (size_t)n * FEAT))[f4];
            uint2 o = make_uint2(pack2(v.x, v.y), pack2(v.z, v.w));
            *(uint2*)(h0 + (size_t)n * FEAT + f4 * 4) = o;
        }
    } else if (b < 2048 + 6250 + 384) {
        int idx = (b - 2048 - 6250) * 256 + threadIdx.x;  // 0..98303
        int layer = idx >> 15;
        int r = idx & 32767;
        int n = r >> 8, k = r & 255;
        const float* wl = (layer == 0) ? wl1 : wl23 + (size_t)(layer - 1) * FEAT * FEAT;
        const float* wr = (layer == 0) ? wr1 : wr23 + (size_t)(layer - 1) * FEAT * FEAT;
        float v = (k < FEAT) ? wl[k * FEAT + n] : wr[(k - FEAT) * FEAT + n];
        wt[idx] = f2bf(v);
    } else {
        int g = (b - 2048 - 6250 - 384) * 256 + threadIdx.x;
        if (g > N_GRAPHS) return;
        int lo = 0, hi = N_NODES;
        while (lo < hi) {
            int mid = (lo + hi) >> 1;
            if (batch[mid] < g) lo = mid + 1; else hi = mid;
        }
        goffs[g] = lo;
    }
}

// ---------- fused SAGE layer: gather-mean -> LDS, then MFMA ----------
// hout = relu([agg | hin] @ Wt^T + b).  hin/hout are distinct buffers
// (ping-pong) because blocks read other blocks' hin rows.
__device__ __forceinline__ void acc8(float* acc, uint4 u) {
    acc[0] += bflo(u.x); acc[1] += bfhi(u.x);
    acc[2] += bflo(u.y); acc[3] += bfhi(u.y);
    acc[4] += bflo(u.z); acc[5] += bfhi(u.z);
    acc[6] += bflo(u.w); acc[7] += bfhi(u.w);
}

__global__ __launch_bounds__(256) void sage_layer(
    const unsigned short* __restrict__ hin, const int* __restrict__ cnt,
    const unsigned short* __restrict__ bucket,
    const unsigned short* __restrict__ Wt, const float* __restrict__ bias,
    unsigned short* __restrict__ hout) {
    __shared__ unsigned short sAgg[TROWS * LROW];
    int t = threadIdx.x;
    int wave = t >> 6, lane = t & 63;
    int g = lane >> 4, l16 = lane & 15;
    int row0 = blockIdx.x * TROWS;

    // ---- phase 1: each wave gather-averages 8 nodes into sAgg ----
    #pragma unroll 1
    for (int rr = 0; rr < 8; ++rr) {
        int r = wave * 8 + rr;
        int n = row0 + r;
        if (n >= N_NODES) break;
        int deg = cnt[n];
        int c = min(deg, BCAP);
        int nq = c >> 2;
        int rem = c & 3;
        const unsigned short* cp = bucket + (size_t)n * BCAP;

        float acc[8];
        #pragma unroll
        for (int i = 0; i < 8; ++i) acc[i] = 0.f;

        int i = 0;
        for (; i + 4 <= nq; i += 4) {
            int s0 = cp[i * 4 + g];
            int s1 = cp[i * 4 + 4 + g];
            int s2 = cp[i * 4 + 8 + g];
            int s3 = cp[i * 4 + 12 + g];
            uint4 u0 = *(const uint4*)(hin + (size_t)s0 * FEAT + l16 * 8);
            uint4 u1 = *(const uint4*)(hin + (size_t)s1 * FEAT + l16 * 8);
            uint4 u2 = *(const uint4*)(hin + (size_t)s2 * FEAT + l16 * 8);
            uint4 u3 = *(const uint4*)(hin + (size_t)s3 * FEAT + l16 * 8);
            acc8(acc, u0); acc8(acc, u1); acc8(acc, u2); acc8(acc, u3);
        }
        if (i + 2 <= nq) {
            int s0 = cp[i * 4 + g];
            int s1 = cp[i * 4 + 4 + g];
            uint4 u0 = *(const uint4*)(hin + (size_t)s0 * FEAT + l16 * 8);
            uint4 u1 = *(const uint4*)(hin + (size_t)s1 * FEAT + l16 * 8);
            acc8(acc, u0); acc8(acc, u1);
            i += 2;
        }
        if (i < nq) {
            int s0 = cp[i * 4 + g];
            uint4 u0 = *(const uint4*)(hin + (size_t)s0 * FEAT + l16 * 8);
            acc8(acc, u0);
        }
        if (g < rem) {
            int s0 = cp[nq * 4 + g];
            uint4 u0 = *(const uint4*)(hin + (size_t)s0 * FEAT + l16 * 8);
            acc8(acc, u0);
        }
        #pragma unroll
        for (int j = 0; j < 8; ++j) {
            acc[j] += __shfl_xor(acc[j], 16);
            acc[j] += __shfl_xor(acc[j], 32);
        }
        if (g == 0) {
            float inv = 1.0f / fmaxf((float)deg, 1.0f);
            uint4 o;
            o.x = pack2(acc[0] * inv, acc[1] * inv);
            o.y = pack2(acc[2] * inv, acc[3] * inv);
            o.z = pack2(acc[4] * inv, acc[5] * inv);
            o.w = pack2(acc[6] * inv, acc[7] * inv);
            *(uint4*)(sAgg + r * LROW + l16 * 8) = o;
        }
    }
    __syncthreads();

    // ---- phase 2: MFMA.  A = [sAgg (k<128) | hin rows (k>=128)],
    // bands: local rows [0,16) and [16,32).  Waves split N: nb = wave*2+{0,1}.
    floatx4 acc2[2][2];
    #pragma unroll
    for (int i = 0; i < 2; ++i)
        #pragma unroll
        for (int j = 0; j < 2; ++j) acc2[i][j] = (floatx4){0.f, 0.f, 0.f, 0.f};

    const unsigned short* ph0 = hin + (size_t)(row0 + l16) * FEAT + g * 8;
    const unsigned short* ph1 = ph0 + 16 * FEAT;
    const unsigned short* pb  = Wt + (size_t)(wave * 32 + l16) * K2 + g * 8;

    #pragma unroll
    for (int ks = 0; ks < 8; ++ks) {
        short8 a0, a1;
        if (ks < 4) {
            a0 = *(const short8*)(sAgg + l16 * LROW + ks * 32 + g * 8);
            a1 = *(const short8*)(sAgg + (16 + l16) * LROW + ks * 32 + g * 8);
        } else {
            a0 = *(const short8*)(ph0 + (ks - 4) * 32);
            a1 = *(const short8*)(ph1 + (ks - 4) * 32);
        }
        #pragma unroll
        for (int j = 0; j < 2; ++j) {
            short8 b = *(const short8*)(pb + (size_t)j * 16 * K2 + ks * 32);
            acc2[0][j] = __builtin_amdgcn_mfma_f32_16x16x32_bf16(a0, b, acc2[0][j], 0, 0, 0);
            acc2[1][j] = __builtin_amdgcn_mfma_f32_16x16x32_bf16(a1, b, acc2[1][j], 0, 0, 0);
        }
    }

    #pragma unroll
    for (int j = 0; j < 2; ++j) {
        int n = wave * 32 + j * 16 + l16;
        float bv = bias[n];
        #pragma unroll
        for (int band = 0; band < 2; ++band) {
            #pragma unroll
            for (int r = 0; r < 4; ++r) {
                int m = row0 + band * 16 + g * 4 + r;
                if (m < N_NODES) {
                    float v = fmaxf(acc2[band][j][r] + bv, 0.f);
                    hout[(size_t)m * FEAT + n] = f2bf(v);
                }
            }
        }
    }
}

// ---------- fused attention pooling: one block (128 thr) per graph ----------
__global__ __launch_bounds__(128) void attn_pool(
    const unsigned short* __restrict__ h, const float* __restrict__ gate_w,
    const float* __restrict__ gate_b, const int* __restrict__ goffs,
    float* __restrict__ gatebuf, float* __restrict__ pooled) {
    __shared__ float red[2], sden[2];
    __shared__ float facc[2][128];
    int g = blockIdx.x;
    int s = goffs[g], e = goffs[g + 1];
    int t = threadIdx.x;
    if (s >= e) { pooled[(size_t)g * FEAT + t] = 0.f; return; }
    int wave = t >> 6, lane = t & 63;
    float2 gw = ((const float2*)gate_w)[lane];
    float gb = gate_b[0];
    float wmax = -INFINITY;
    for (int n = s + wave; n < e; n += 2) {
        unsigned u = *(const unsigned*)(h + (size_t)n * FEAT + lane * 2);
        float gv = bflo(u) * gw.x + bfhi(u) * gw.y;
        #pragma unroll
        for (int off = 32; off; off >>= 1) gv += __shfl_xor(gv, off);
        gv += gb;
        if (lane == 0) gatebuf[n] = gv;
        wmax = fmaxf(wmax, gv);
    }
    if (lane == 0) red[wave] = wmax;
    __syncthreads();
    float m = fmaxf(red[0], red[1]);
    float d = 0.f;
    for (int n = s + t; n < e; n += 128) {
        float ev = __expf(gatebuf[n] - m);
        gatebuf[n] = ev;
        d += ev;
    }
    #pragma unroll
    for (int off = 32; off; off >>= 1) d += __shfl_xor(d, off);
    if (lane == 0) sden[wave] = d;
    __syncthreads();
    float den = sden[0] + sden[1];
    float acc0 = 0.f, acc1 = 0.f;
    for (int n = s + wave; n < e; n += 2) {
        float gn = gatebuf[n];
        unsigned u = *(const unsigned*)(h + (size_t)n * FEAT + lane * 2);
        acc0 += gn * bflo(u);
        acc1 += gn * bfhi(u);
    }
    facc[wave][lane * 2]     = acc0;
    facc[wave][lane * 2 + 1] = acc1;
    __syncthreads();
    pooled[(size_t)g * FEAT + t] = (facc[0][t] + facc[1][t]) / den;
}

// ---------- head: relu(pooled@lin1+b1) @ lin2 + b2 -> log_softmax ----------
__global__ __launch_bounds__(128) void head_kernel(
    const float* __restrict__ pooled,
    const float* __restrict__ w1, const float* __restrict__ b1,
    const float* __restrict__ w2, const float* __restrict__ b2,
    float* __restrict__ out) {
    __shared__ float p[128], qv[128], lg[N_CLASSES];
    int g = blockIdx.x;
    int t = threadIdx.x;
    p[t] = pooled[(size_t)g * FEAT + t];
    __syncthreads();
    float acc = b1[t];
    #pragma unroll 4
    for (int k = 0; k < 128; ++k) acc += p[k] * w1[k * FEAT + t];
    qv[t] = fmaxf(acc, 0.f);
    __syncthreads();
    if (t < N_CLASSES) {
        float a = b2[t];
        #pragma unroll 4
        for (int k = 0; k < 128; ++k) a += qv[k] * w2[k * N_CLASSES + t];
        lg[t] = a;
    }
    __syncthreads();
    if (t < N_CLASSES) {
        float m = -INFINITY;
        #pragma unroll
        for (int j = 0; j < N_CLASSES; ++j) m = fmaxf(m, lg[j]);
        float sum = 0.f;
        #pragma unroll
        for (int j = 0; j < N_CLASSES; ++j) sum += __expf(lg[j] - m);
        out[(size_t)g * N_CLASSES + t] = lg[t] - m - __logf(sum);
    }
}

// ---------- launch ----------
static inline size_t align256(size_t x) { return (x + 255) & ~(size_t)255; }

extern "C" void kernel_launch(void* const* d_in, const int* in_sizes, int n_in,
                              void* d_out, int out_size, void* d_ws, size_t ws_size,
                              hipStream_t stream) {
    const float* x        = (const float*)d_in[0];
    const int*   ei       = (const int*)d_in[1];
    const int*   batch    = (const int*)d_in[2];
    const float* conv1_wl = (const float*)d_in[4];
    const float* conv1_wr = (const float*)d_in[5];
    const float* conv1_b  = (const float*)d_in[6];
    const float* convs_wl = (const float*)d_in[7];
    const float* convs_wr = (const float*)d_in[8];
    const float* convs_b  = (const float*)d_in[9];
    const float* gate_w   = (const float*)d_in[10];
    const float* gate_b   = (const float*)d_in[11];
    const float* lin1_w   = (const float*)d_in[12];
    const float* lin1_b   = (const float*)d_in[13];
    const float* lin2_w   = (const float*)d_in[14];
    const float* lin2_b   = (const float*)d_in[15];
    float* out = (float*)d_out;

    const int* src = ei;
    const int* dst = ei + N_EDGES;

    char* w = (char*)d_ws;
    size_t off = 0;
    unsigned short* h0   = (unsigned short*)(w + off); off += align256((size_t)N_PAD * FEAT * 2);
    unsigned short* h1   = (unsigned short*)(w + off); off += align256((size_t)N_PAD * FEAT * 2);
    unsigned short* bkt  = (unsigned short*)(w + off); off += align256((size_t)N_NODES * BCAP * 2);
    unsigned short* wt   = (unsigned short*)(w + off); off += align256((size_t)3 * FEAT * K2 * 2);
    int*   i_cnt  = (int*)(w + off);   off += align256((size_t)N_NODES * 4);
    float* f_gate = (float*)(w + off); off += align256((size_t)N_NODES * 4);
    int*   i_goff = (int*)(w + off);   off += align256((size_t)(N_GRAPHS + 1) * 4);
    float* f_pool = (float*)(w + off); off += align256((size_t)N_GRAPHS * FEAT * 4);

    hipMemsetAsync(i_cnt, 0, (size_t)N_NODES * 4, stream);

    fill_setup<<<2048 + 6250 + 384 + 3, 256, 0, stream>>>(
        src, dst, i_cnt, bkt, x, h0, conv1_wl, conv1_wr, convs_wl, convs_wr,
        wt, batch, i_goff);

    const int LB = N_PAD / TROWS;  // 1564

    sage_layer<<<LB, 256, 0, stream>>>(h0, i_cnt, bkt, wt, conv1_b, h1);
    sage_layer<<<LB, 256, 0, stream>>>(h1, i_cnt, bkt, wt + FEAT * K2, convs_b, h0);
    sage_layer<<<LB, 256, 0, stream>>>(h0, i_cnt, bkt, wt + 2 * FEAT * K2,
                                       convs_b + FEAT, h1);

    attn_pool<<<N_GRAPHS, 128, 0, stream>>>(h1, gate_w, gate_b, i_goff,
                                            f_gate, f_pool);
    head_kernel<<<N_GRAPHS, 128, 0, stream>>>(f_pool, lin1_w, lin1_b, lin2_w, lin2_b, out);
}

// Round 7
// 369.852 us; speedup vs baseline: 1.0392x; 1.0392x over previous
//
#include <hip/hip_runtime.h>
#include <math.h>

#define N_NODES 50000
#define N_PAD   50048
#define N_EDGES 800000
#define FEAT 128
#define K2 256
#define N_GRAPHS 512
#define N_CLASSES 10
#define BCAP 64          // bucket capacity (deg ~ Poisson(16); P(>64) ~ 0)
#define RANGE_SZ 12500   // 50000 / 4 dst ranges (1.6 MB ushort slice < 4 MB L2)
#define FILL_CHUNK 1600  // 800000 / 500 chunks
#define FILL_BLKS 2000   // 4 ranges x 500 chunks

typedef __attribute__((ext_vector_type(8))) short short8;
typedef __attribute__((ext_vector_type(4))) float floatx4;

// ---------- bf16 helpers ----------
__device__ __forceinline__ float bflo(unsigned u) { return __uint_as_float(u << 16); }
__device__ __forceinline__ float bfhi(unsigned u) { return __uint_as_float(u & 0xffff0000u); }
__device__ __forceinline__ unsigned short f2bf(float f) {
    unsigned u = __float_as_uint(f);
    u = (u + 0x7fffu + ((u >> 16) & 1u)) >> 16;   // RNE
    return (unsigned short)u;
}
__device__ __forceinline__ unsigned pack2(float a, float b) {
    return (unsigned)f2bf(a) | ((unsigned)f2bf(b) << 16);
}

// ---------- fused graph setup + conversions ----------
// blocks [0,2000): dst-range bucket fill. range = b&3; XCD = b&7 (each XCD
//   serves exactly one range; its 1.6 MB ushort bucket slice stays L2-resident
//   so the ~16 writes per node's bucket line merge before writeback).
// blocks [2000, 2000+6250): x -> bf16 dense h
// next 384: weight transpose+concat -> bf16 Wt[layer][n][k]
// last 3: goffs binary search
__global__ __launch_bounds__(256) void fill_setup(
    const int* __restrict__ src, const int* __restrict__ dst,
    int* __restrict__ cnt, unsigned short* __restrict__ bucket,
    const float* __restrict__ x, unsigned short* __restrict__ h,
    const float* __restrict__ wl1, const float* __restrict__ wr1,
    const float* __restrict__ wl23, const float* __restrict__ wr23,
    unsigned short* __restrict__ wt,
    const int* __restrict__ batch, int* __restrict__ goffs) {
    int b = blockIdx.x;
    if (b < FILL_BLKS) {
        int range = b & 3;
        int chunk = b >> 2;           // 0..499
        int lo = range * RANGE_SZ, hi = lo + RANGE_SZ;
        int e0 = chunk * FILL_CHUNK;
        int e1 = e0 + FILL_CHUNK;
        for (int e = e0 + threadIdx.x; e < e1; e += 256) {
            int d = dst[e];
            if (d >= lo && d < hi) {
                int p = atomicAdd(&cnt[d], 1);
                if (p < BCAP) bucket[(size_t)d * BCAP + p] = (unsigned short)src[e];
            }
        }
    } else if (b < FILL_BLKS + 6250) {
        int idx = (b - FILL_BLKS) * 256 + threadIdx.x;   // n*32 + f4
        if (idx < N_NODES * 32) {
            int n = idx >> 5, f4 = idx & 31;
            float4 v = ((const float4*)(x + (size_t)n * FEAT))[f4];
            uint2 o = make_uint2(pack2(v.x, v.y), pack2(v.z, v.w));
            *(uint2*)(h + (size_t)n * FEAT + f4 * 4) = o;
        }
    } else if (b < FILL_BLKS + 6250 + 384) {
        int idx = (b - FILL_BLKS - 6250) * 256 + threadIdx.x;  // 0..98303
        int layer = idx >> 15;
        int r = idx & 32767;
        int n = r >> 8, k = r & 255;
        const float* wl = (layer == 0) ? wl1 : wl23 + (size_t)(layer - 1) * FEAT * FEAT;
        const float* wr = (layer == 0) ? wr1 : wr23 + (size_t)(layer - 1) * FEAT * FEAT;
        float v = (k < FEAT) ? wl[k * FEAT + n] : wr[(k - FEAT) * FEAT + n];
        wt[idx] = f2bf(v);
    } else {
        int g = (b - FILL_BLKS - 6250 - 384) * 256 + threadIdx.x;
        if (g > N_GRAPHS) return;
        int lo = 0, hi = N_NODES;
        while (lo < hi) {
            int mid = (lo + hi) >> 1;
            if (batch[mid] < g) lo = mid + 1; else hi = mid;
        }
        goffs[g] = lo;
    }
}

// ---------- aggregation: wave = node; 16-lane groups, dwordx4 gathers ----------
// agg[n] = mean over in-edges of h[src].  12500 blocks x 4 waves for TLP.
__device__ __forceinline__ void acc8(float* acc, uint4 u) {
    acc[0] += bflo(u.x); acc[1] += bfhi(u.x);
    acc[2] += bflo(u.y); acc[3] += bfhi(u.y);
    acc[4] += bflo(u.z); acc[5] += bfhi(u.z);
    acc[6] += bflo(u.w); acc[7] += bfhi(u.w);
}

__global__ __launch_bounds__(256) void aggregate_bf16(
    const unsigned short* __restrict__ h, const int* __restrict__ cnt,
    const unsigned short* __restrict__ bucket, unsigned short* __restrict__ agg) {
    int n = blockIdx.x * 4 + (threadIdx.x >> 6);
    if (n >= N_NODES) return;
    int lane = threadIdx.x & 63;
    int g = lane >> 4;        // edge slot within quad
    int l16 = lane & 15;      // 16 lanes x 16 B = 256 B row
    int deg = cnt[n];
    int c = min(deg, BCAP);
    int nq = c >> 2;
    int rem = c & 3;
    const unsigned short* cp = bucket + (size_t)n * BCAP;

    float acc[8];
    #pragma unroll
    for (int i = 0; i < 8; ++i) acc[i] = 0.f;

    int i = 0;
    for (; i + 4 <= nq; i += 4) {
        int s0 = cp[i * 4 + g];
        int s1 = cp[i * 4 + 4 + g];
        int s2 = cp[i * 4 + 8 + g];
        int s3 = cp[i * 4 + 12 + g];
        uint4 u0 = *(const uint4*)(h + (size_t)s0 * FEAT + l16 * 8);
        uint4 u1 = *(const uint4*)(h + (size_t)s1 * FEAT + l16 * 8);
        uint4 u2 = *(const uint4*)(h + (size_t)s2 * FEAT + l16 * 8);
        uint4 u3 = *(const uint4*)(h + (size_t)s3 * FEAT + l16 * 8);
        acc8(acc, u0); acc8(acc, u1); acc8(acc, u2); acc8(acc, u3);
    }
    if (i + 2 <= nq) {
        int s0 = cp[i * 4 + g];
        int s1 = cp[i * 4 + 4 + g];
        uint4 u0 = *(const uint4*)(h + (size_t)s0 * FEAT + l16 * 8);
        uint4 u1 = *(const uint4*)(h + (size_t)s1 * FEAT + l16 * 8);
        acc8(acc, u0); acc8(acc, u1);
        i += 2;
    }
    if (i < nq) {
        int s0 = cp[i * 4 + g];
        uint4 u0 = *(const uint4*)(h + (size_t)s0 * FEAT + l16 * 8);
        acc8(acc, u0);
    }
    if (g < rem) {
        int s0 = cp[nq * 4 + g];
        uint4 u0 = *(const uint4*)(h + (size_t)s0 * FEAT + l16 * 8);
        acc8(acc, u0);
    }
    #pragma unroll
    for (int j = 0; j < 8; ++j) {
        acc[j] += __shfl_xor(acc[j], 16);
        acc[j] += __shfl_xor(acc[j], 32);
    }
    if (g == 0) {
        float inv = 1.0f / fmaxf((float)deg, 1.0f);
        uint4 o;
        o.x = pack2(acc[0] * inv, acc[1] * inv);
        o.y = pack2(acc[2] * inv, acc[3] * inv);
        o.z = pack2(acc[4] * inv, acc[5] * inv);
        o.w = pack2(acc[6] * inv, acc[7] * inv);
        *(uint4*)(agg + (size_t)n * FEAT + l16 * 8) = o;
    }
}

// ---------- MFMA GEMM: h = relu([agg|h] @ Wt^T + b), in place ----------
// Each block covers 128 rows and reads ONLY those rows; all A-fragments are
// preloaded to registers, then __syncthreads(), then MFMA + store — so the
// in-place update of h cannot race within or across blocks.
__global__ __launch_bounds__(256) void gemm_mfma(
    const unsigned short* __restrict__ agg, unsigned short* __restrict__ h,
    const unsigned short* __restrict__ Wt, const float* __restrict__ bias) {
    int wave = threadIdx.x >> 6, lane = threadIdx.x & 63;
    int q = lane >> 4, l16 = lane & 15;
    int row0 = blockIdx.x * 128 + wave * 32;
    const unsigned short* pa0 = agg + (size_t)(row0 + l16) * FEAT + q * 8;
    const unsigned short* pa1 = pa0 + 16 * FEAT;
    const unsigned short* ph0 = h + (size_t)(row0 + l16) * FEAT + q * 8;
    const unsigned short* ph1 = ph0 + 16 * FEAT;
    const unsigned short* pb  = Wt + (size_t)l16 * K2 + q * 8;

    // preload all A fragments (2 bands x 8 k-steps)
    short8 a0[8], a1[8];
    #pragma unroll
    for (int ks = 0; ks < 4; ++ks) {
        a0[ks] = *(const short8*)(pa0 + ks * 32);
        a1[ks] = *(const short8*)(pa1 + ks * 32);
        a0[4 + ks] = *(const short8*)(ph0 + ks * 32);
        a1[4 + ks] = *(const short8*)(ph1 + ks * 32);
    }
    __syncthreads();   // all loads of this block's rows complete before stores

    floatx4 acc[2][8];
    #pragma unroll
    for (int i = 0; i < 2; ++i)
        #pragma unroll
        for (int j = 0; j < 8; ++j) acc[i][j] = (floatx4){0.f, 0.f, 0.f, 0.f};

    #pragma unroll
    for (int ks = 0; ks < 8; ++ks) {
        #pragma unroll
        for (int nb = 0; nb < 8; ++nb) {
            short8 b = *(const short8*)(pb + (size_t)nb * 16 * K2 + ks * 32);
            acc[0][nb] = __builtin_amdgcn_mfma_f32_16x16x32_bf16(a0[ks], b, acc[0][nb], 0, 0, 0);
            acc[1][nb] = __builtin_amdgcn_mfma_f32_16x16x32_bf16(a1[ks], b, acc[1][nb], 0, 0, 0);
        }
    }

    #pragma unroll
    for (int nb = 0; nb < 8; ++nb) {
        int ncol = nb * 16 + l16;
        float bv = bias[ncol];
        #pragma unroll
        for (int band = 0; band < 2; ++band) {
            #pragma unroll
            for (int r = 0; r < 4; ++r) {
                int m = row0 + band * 16 + q * 4 + r;
                if (m < N_NODES) {
                    float v = fmaxf(acc[band][nb][r] + bv, 0.f);
                    h[(size_t)m * FEAT + ncol] = f2bf(v);
                }
            }
        }
    }
}

// ---------- fused attention pooling: one block (128 thr) per graph ----------
__global__ __launch_bounds__(128) void attn_pool(
    const unsigned short* __restrict__ h, const float* __restrict__ gate_w,
    const float* __restrict__ gate_b, const int* __restrict__ goffs,
    float* __restrict__ gatebuf, float* __restrict__ pooled) {
    __shared__ float red[2], sden[2];
    __shared__ float facc[2][128];
    int g = blockIdx.x;
    int s = goffs[g], e = goffs[g + 1];
    int t = threadIdx.x;
    if (s >= e) { pooled[(size_t)g * FEAT + t] = 0.f; return; }
    int wave = t >> 6, lane = t & 63;
    float2 gw = ((const float2*)gate_w)[lane];
    float gb = gate_b[0];
    float wmax = -INFINITY;
    for (int n = s + wave; n < e; n += 2) {
        unsigned u = *(const unsigned*)(h + (size_t)n * FEAT + lane * 2);
        float gv = bflo(u) * gw.x + bfhi(u) * gw.y;
        #pragma unroll
        for (int off = 32; off; off >>= 1) gv += __shfl_xor(gv, off);
        gv += gb;
        if (lane == 0) gatebuf[n] = gv;
        wmax = fmaxf(wmax, gv);
    }
    if (lane == 0) red[wave] = wmax;
    __syncthreads();
    float m = fmaxf(red[0], red[1]);
    float d = 0.f;
    for (int n = s + t; n < e; n += 128) {
        float ev = __expf(gatebuf[n] - m);
        gatebuf[n] = ev;
        d += ev;
    }
    #pragma unroll
    for (int off = 32; off; off >>= 1) d += __shfl_xor(d, off);
    if (lane == 0) sden[wave] = d;
    __syncthreads();
    float den = sden[0] + sden[1];
    float acc0 = 0.f, acc1 = 0.f;
    for (int n = s + wave; n < e; n += 2) {
        float gn = gatebuf[n];
        unsigned u = *(const unsigned*)(h + (size_t)n * FEAT + lane * 2);
        acc0 += gn * bflo(u);
        acc1 += gn * bfhi(u);
    }
    facc[wave][lane * 2]     = acc0;
    facc[wave][lane * 2 + 1] = acc1;
    __syncthreads();
    pooled[(size_t)g * FEAT + t] = (facc[0][t] + facc[1][t]) / den;
}

// ---------- head: relu(pooled@lin1+b1) @ lin2 + b2 -> log_softmax ----------
__global__ __launch_bounds__(128) void head_kernel(
    const float* __restrict__ pooled,
    const float* __restrict__ w1, const float* __restrict__ b1,
    const float* __restrict__ w2, const float* __restrict__ b2,
    float* __restrict__ out) {
    __shared__ float p[128], qv[128], lg[N_CLASSES];
    int g = blockIdx.x;
    int t = threadIdx.x;
    p[t] = pooled[(size_t)g * FEAT + t];
    __syncthreads();
    float acc = b1[t];
    #pragma unroll 4
    for (int k = 0; k < 128; ++k) acc += p[k] * w1[k * FEAT + t];
    qv[t] = fmaxf(acc, 0.f);
    __syncthreads();
    if (t < N_CLASSES) {
        float a = b2[t];
        #pragma unroll 4
        for (int k = 0; k < 128; ++k) a += qv[k] * w2[k * N_CLASSES + t];
        lg[t] = a;
    }
    __syncthreads();
    if (t < N_CLASSES) {
        float m = -INFINITY;
        #pragma unroll
        for (int j = 0; j < N_CLASSES; ++j) m = fmaxf(m, lg[j]);
        float sum = 0.f;
        #pragma unroll
        for (int j = 0; j < N_CLASSES; ++j) sum += __expf(lg[j] - m);
        out[(size_t)g * N_CLASSES + t] = lg[t] - m - __logf(sum);
    }
}

// ---------- launch ----------
static inline size_t align256(size_t x) { return (x + 255) & ~(size_t)255; }

extern "C" void kernel_launch(void* const* d_in, const int* in_sizes, int n_in,
                              void* d_out, int out_size, void* d_ws, size_t ws_size,
                              hipStream_t stream) {
    const float* x        = (const float*)d_in[0];
    const int*   ei       = (const int*)d_in[1];
    const int*   batch    = (const int*)d_in[2];
    const float* conv1_wl = (const float*)d_in[4];
    const float* conv1_wr = (const float*)d_in[5];
    const float* conv1_b  = (const float*)d_in[6];
    const float* convs_wl = (const float*)d_in[7];
    const float* convs_wr = (const float*)d_in[8];
    const float* convs_b  = (const float*)d_in[9];
    const float* gate_w   = (const float*)d_in[10];
    const float* gate_b   = (const float*)d_in[11];
    const float* lin1_w   = (const float*)d_in[12];
    const float* lin1_b   = (const float*)d_in[13];
    const float* lin2_w   = (const float*)d_in[14];
    const float* lin2_b   = (const float*)d_in[15];
    float* out = (float*)d_out;

    const int* src = ei;
    const int* dst = ei + N_EDGES;

    char* w = (char*)d_ws;
    size_t off = 0;
    unsigned short* h    = (unsigned short*)(w + off); off += align256((size_t)N_PAD * FEAT * 2);
    unsigned short* agg  = (unsigned short*)(w + off); off += align256((size_t)N_PAD * FEAT * 2);
    unsigned short* bkt  = (unsigned short*)(w + off); off += align256((size_t)N_NODES * BCAP * 2);
    unsigned short* wt   = (unsigned short*)(w + off); off += align256((size_t)3 * FEAT * K2 * 2);
    int*   i_cnt  = (int*)(w + off);   off += align256((size_t)N_NODES * 4);
    float* f_gate = (float*)(w + off); off += align256((size_t)N_NODES * 4);
    int*   i_goff = (int*)(w + off);   off += align256((size_t)(N_GRAPHS + 1) * 4);
    float* f_pool = (float*)(w + off); off += align256((size_t)N_GRAPHS * FEAT * 4);

    hipMemsetAsync(i_cnt, 0, (size_t)N_NODES * 4, stream);

    fill_setup<<<FILL_BLKS + 6250 + 384 + 3, 256, 0, stream>>>(
        src, dst, i_cnt, bkt, x, h, conv1_wl, conv1_wr, convs_wl, convs_wr,
        wt, batch, i_goff);

    const int AB = (N_NODES + 3) / 4;   // 12500
    const int GB = N_PAD / 128;         // 391

    aggregate_bf16<<<AB, 256, 0, stream>>>(h, i_cnt, bkt, agg);
    gemm_mfma<<<GB, 256, 0, stream>>>(agg, h, wt, conv1_b);
    aggregate_bf16<<<AB, 256, 0, stream>>>(h, i_cnt, bkt, agg);
    gemm_mfma<<<GB, 256, 0, stream>>>(agg, h, wt + FEAT * K2, convs_b);
    aggregate_bf16<<<AB, 256, 0, stream>>>(h, i_cnt, bkt, agg);
    gemm_mfma<<<GB, 256, 0, stream>>>(agg, h, wt + 2 * FEAT * K2, convs_b + FEAT);

    attn_pool<<<N_GRAPHS, 128, 0, stream>>>(h, gate_w, gate_b, i_goff,
                                            f_gate, f_pool);
    head_kernel<<<N_GRAPHS, 128, 0, stream>>>(f_pool, lin1_w, lin1_b, lin2_w, lin2_b, out);
}

// Round 8
// 367.570 us; speedup vs baseline: 1.0457x; 1.0062x over previous
//
#include <hip/hip_runtime.h>
#include <math.h>

#define N_NODES 50000
#define N_PAD   50048
#define N_EDGES 800000
#define FEAT 128
#define K2 256
#define N_GRAPHS 512
#define N_CLASSES 10
#define BCAP 64          // bucket capacity (deg ~ Poisson(16); P(>64) ~ 0)
#define RANGE_SZ 12500   // 50000 / 4 dst ranges (1.6 MB ushort slice per range)

typedef __attribute__((ext_vector_type(8))) short short8;
typedef __attribute__((ext_vector_type(4))) float floatx4;

// ---------- bf16 helpers ----------
__device__ __forceinline__ float bflo(unsigned u) { return __uint_as_float(u << 16); }
__device__ __forceinline__ float bfhi(unsigned u) { return __uint_as_float(u & 0xffff0000u); }
__device__ __forceinline__ unsigned short f2bf(float f) {
    unsigned u = __float_as_uint(f);
    u = (u + 0x7fffu + ((u >> 16) & 1u)) >> 16;   // RNE
    return (unsigned short)u;
}
__device__ __forceinline__ unsigned pack2(float a, float b) {
    return (unsigned)f2bf(a) | ((unsigned)f2bf(b) << 16);
}

// ---------- bucket fill: one edge per thread, dst-range partitioned ----------
// range = blockIdx&3; XCDs {r, r+4} serve range r (blockIdx&7 ~ XCD), so each
// range's 1.6 MB ushort bucket slice + cnt lines stay L2-resident in 2 XCDs
// and the ~16 writes per node's bucket line merge before writeback. This
// kernel runs ALONE so no streaming traffic evicts the slice.
__global__ __launch_bounds__(256) void fill_bucket(
    const int* __restrict__ src, const int* __restrict__ dst,
    int* __restrict__ cnt, unsigned short* __restrict__ bucket) {
    int range = blockIdx.x & 3;
    int chunk = blockIdx.x >> 2;            // 0..3124
    int e = chunk * 256 + threadIdx.x;      // one edge per thread
    int lo = range * RANGE_SZ;
    int d = dst[e];
    if (d >= lo && d < lo + RANGE_SZ) {
        int p = atomicAdd(&cnt[d], 1);
        if (p < BCAP) bucket[(size_t)d * BCAP + p] = (unsigned short)src[e];
    }
}

// ---------- setup: x->bf16 | weight transpose+concat | goffs ----------
__global__ __launch_bounds__(256) void setup_kernel(
    const float* __restrict__ x, unsigned short* __restrict__ h,
    const float* __restrict__ wl1, const float* __restrict__ wr1,
    const float* __restrict__ wl23, const float* __restrict__ wr23,
    unsigned short* __restrict__ wt,
    const int* __restrict__ batch, int* __restrict__ goffs) {
    int b = blockIdx.x;
    if (b < 6250) {
        int idx = b * 256 + threadIdx.x;   // n*32 + f4
        if (idx < N_NODES * 32) {
            int n = idx >> 5, f4 = idx & 31;
            float4 v = ((const float4*)(x + (size_t)n * FEAT))[f4];
            uint2 o = make_uint2(pack2(v.x, v.y), pack2(v.z, v.w));
            *(uint2*)(h + (size_t)n * FEAT + f4 * 4) = o;
        }
    } else if (b < 6250 + 384) {
        int idx = (b - 6250) * 256 + threadIdx.x;  // 0..98303
        int layer = idx >> 15;
        int r = idx & 32767;
        int n = r >> 8, k = r & 255;
        const float* wl = (layer == 0) ? wl1 : wl23 + (size_t)(layer - 1) * FEAT * FEAT;
        const float* wr = (layer == 0) ? wr1 : wr23 + (size_t)(layer - 1) * FEAT * FEAT;
        float v = (k < FEAT) ? wl[k * FEAT + n] : wr[(k - FEAT) * FEAT + n];
        wt[idx] = f2bf(v);
    } else {
        int g = (b - 6250 - 384) * 256 + threadIdx.x;
        if (g > N_GRAPHS) return;
        int lo = 0, hi = N_NODES;
        while (lo < hi) {
            int mid = (lo + hi) >> 1;
            if (batch[mid] < g) lo = mid + 1; else hi = mid;
        }
        goffs[g] = lo;
    }
}

// ---------- aggregation: wave = node; 16-lane groups, dwordx4 gathers ----------
__device__ __forceinline__ void acc8(float* acc, uint4 u) {
    acc[0] += bflo(u.x); acc[1] += bfhi(u.x);
    acc[2] += bflo(u.y); acc[3] += bfhi(u.y);
    acc[4] += bflo(u.z); acc[5] += bfhi(u.z);
    acc[6] += bflo(u.w); acc[7] += bfhi(u.w);
}

__global__ __launch_bounds__(256) void aggregate_bf16(
    const unsigned short* __restrict__ h, const int* __restrict__ cnt,
    const unsigned short* __restrict__ bucket, unsigned short* __restrict__ agg) {
    int n = blockIdx.x * 4 + (threadIdx.x >> 6);
    if (n >= N_NODES) return;
    int lane = threadIdx.x & 63;
    int g = lane >> 4;        // edge slot within quad
    int l16 = lane & 15;      // 16 lanes x 16 B = 256 B row
    int deg = cnt[n];
    int c = min(deg, BCAP);
    int nq = c >> 2;
    int rem = c & 3;
    const unsigned short* cp = bucket + (size_t)n * BCAP;

    float acc[8];
    #pragma unroll
    for (int i = 0; i < 8; ++i) acc[i] = 0.f;

    int i = 0;
    for (; i + 4 <= nq; i += 4) {
        int s0 = cp[i * 4 + g];
        int s1 = cp[i * 4 + 4 + g];
        int s2 = cp[i * 4 + 8 + g];
        int s3 = cp[i * 4 + 12 + g];
        uint4 u0 = *(const uint4*)(h + (size_t)s0 * FEAT + l16 * 8);
        uint4 u1 = *(const uint4*)(h + (size_t)s1 * FEAT + l16 * 8);
        uint4 u2 = *(const uint4*)(h + (size_t)s2 * FEAT + l16 * 8);
        uint4 u3 = *(const uint4*)(h + (size_t)s3 * FEAT + l16 * 8);
        acc8(acc, u0); acc8(acc, u1); acc8(acc, u2); acc8(acc, u3);
    }
    if (i + 2 <= nq) {
        int s0 = cp[i * 4 + g];
        int s1 = cp[i * 4 + 4 + g];
        uint4 u0 = *(const uint4*)(h + (size_t)s0 * FEAT + l16 * 8);
        uint4 u1 = *(const uint4*)(h + (size_t)s1 * FEAT + l16 * 8);
        acc8(acc, u0); acc8(acc, u1);
        i += 2;
    }
    if (i < nq) {
        int s0 = cp[i * 4 + g];
        uint4 u0 = *(const uint4*)(h + (size_t)s0 * FEAT + l16 * 8);
        acc8(acc, u0);
    }
    if (g < rem) {
        int s0 = cp[nq * 4 + g];
        uint4 u0 = *(const uint4*)(h + (size_t)s0 * FEAT + l16 * 8);
        acc8(acc, u0);
    }
    #pragma unroll
    for (int j = 0; j < 8; ++j) {
        acc[j] += __shfl_xor(acc[j], 16);
        acc[j] += __shfl_xor(acc[j], 32);
    }
    if (g == 0) {
        float inv = 1.0f / fmaxf((float)deg, 1.0f);
        uint4 o;
        o.x = pack2(acc[0] * inv, acc[1] * inv);
        o.y = pack2(acc[2] * inv, acc[3] * inv);
        o.z = pack2(acc[4] * inv, acc[5] * inv);
        o.w = pack2(acc[6] * inv, acc[7] * inv);
        *(uint4*)(agg + (size_t)n * FEAT + l16 * 8) = o;
    }
}

// ---------- MFMA GEMM: h = relu([agg|h] @ Wt^T + b), in place ----------
// Each block reads ONLY its own 128 rows; A-fragments preloaded to registers
// before any store, so the in-place update cannot race.
__global__ __launch_bounds__(256) void gemm_mfma(
    const unsigned short* __restrict__ agg, unsigned short* __restrict__ h,
    const unsigned short* __restrict__ Wt, const float* __restrict__ bias) {
    int wave = threadIdx.x >> 6, lane = threadIdx.x & 63;
    int q = lane >> 4, l16 = lane & 15;
    int row0 = blockIdx.x * 128 + wave * 32;
    const unsigned short* pa0 = agg + (size_t)(row0 + l16) * FEAT + q * 8;
    const unsigned short* pa1 = pa0 + 16 * FEAT;
    const unsigned short* ph0 = h + (size_t)(row0 + l16) * FEAT + q * 8;
    const unsigned short* ph1 = ph0 + 16 * FEAT;
    const unsigned short* pb  = Wt + (size_t)l16 * K2 + q * 8;

    short8 a0[8], a1[8];
    #pragma unroll
    for (int ks = 0; ks < 4; ++ks) {
        a0[ks] = *(const short8*)(pa0 + ks * 32);
        a1[ks] = *(const short8*)(pa1 + ks * 32);
        a0[4 + ks] = *(const short8*)(ph0 + ks * 32);
        a1[4 + ks] = *(const short8*)(ph1 + ks * 32);
    }
    __syncthreads();

    floatx4 acc[2][8];
    #pragma unroll
    for (int i = 0; i < 2; ++i)
        #pragma unroll
        for (int j = 0; j < 8; ++j) acc[i][j] = (floatx4){0.f, 0.f, 0.f, 0.f};

    #pragma unroll
    for (int ks = 0; ks < 8; ++ks) {
        #pragma unroll
        for (int nb = 0; nb < 8; ++nb) {
            short8 b = *(const short8*)(pb + (size_t)nb * 16 * K2 + ks * 32);
            acc[0][nb] = __builtin_amdgcn_mfma_f32_16x16x32_bf16(a0[ks], b, acc[0][nb], 0, 0, 0);
            acc[1][nb] = __builtin_amdgcn_mfma_f32_16x16x32_bf16(a1[ks], b, acc[1][nb], 0, 0, 0);
        }
    }

    #pragma unroll
    for (int nb = 0; nb < 8; ++nb) {
        int ncol = nb * 16 + l16;
        float bv = bias[ncol];
        #pragma unroll
        for (int band = 0; band < 2; ++band) {
            #pragma unroll
            for (int r = 0; r < 4; ++r) {
                int m = row0 + band * 16 + q * 4 + r;
                if (m < N_NODES) {
                    float v = fmaxf(acc[band][nb][r] + bv, 0.f);
                    h[(size_t)m * FEAT + ncol] = f2bf(v);
                }
            }
        }
    }
}

// ---------- fused attention pooling + MLP head, one block per graph ----------
__global__ __launch_bounds__(128) void pool_head(
    const unsigned short* __restrict__ h, const float* __restrict__ gate_w,
    const float* __restrict__ gate_b, const int* __restrict__ goffs,
    float* __restrict__ gatebuf,
    const float* __restrict__ w1, const float* __restrict__ b1,
    const float* __restrict__ w2, const float* __restrict__ b2,
    float* __restrict__ out) {
    __shared__ float red[2], sden[2];
    __shared__ float facc[2][128];
    __shared__ float pv[128], qv[128], lg[N_CLASSES];
    int g = blockIdx.x;
    int s = goffs[g], e = goffs[g + 1];
    int t = threadIdx.x;
    int wave = t >> 6, lane = t & 63;

    if (s < e) {
        float2 gw = ((const float2*)gate_w)[lane];
        float gb = gate_b[0];
        float wmax = -INFINITY;
        for (int n = s + wave; n < e; n += 2) {
            unsigned u = *(const unsigned*)(h + (size_t)n * FEAT + lane * 2);
            float gv = bflo(u) * gw.x + bfhi(u) * gw.y;
            #pragma unroll
            for (int off = 32; off; off >>= 1) gv += __shfl_xor(gv, off);
            gv += gb;
            if (lane == 0) gatebuf[n] = gv;
            wmax = fmaxf(wmax, gv);
        }
        if (lane == 0) red[wave] = wmax;
        __syncthreads();
        float m = fmaxf(red[0], red[1]);
        float d = 0.f;
        for (int n = s + t; n < e; n += 128) {
            float ev = __expf(gatebuf[n] - m);
            gatebuf[n] = ev;
            d += ev;
        }
        #pragma unroll
        for (int off = 32; off; off >>= 1) d += __shfl_xor(d, off);
        if (lane == 0) sden[wave] = d;
        __syncthreads();
        float den = sden[0] + sden[1];
        float acc0 = 0.f, acc1 = 0.f;
        for (int n = s + wave; n < e; n += 2) {
            float gn = gatebuf[n];
            unsigned u = *(const unsigned*)(h + (size_t)n * FEAT + lane * 2);
            acc0 += gn * bflo(u);
            acc1 += gn * bfhi(u);
        }
        facc[wave][lane * 2]     = acc0;
        facc[wave][lane * 2 + 1] = acc1;
        __syncthreads();
        pv[t] = (facc[0][t] + facc[1][t]) / den;
    } else {
        pv[t] = 0.f;
    }
    __syncthreads();

    // head: q = relu(pv @ w1 + b1); logits = q @ w2 + b2; log_softmax
    float acc = b1[t];
    #pragma unroll 4
    for (int k = 0; k < 128; ++k) acc += pv[k] * w1[k * FEAT + t];
    qv[t] = fmaxf(acc, 0.f);
    __syncthreads();
    if (t < N_CLASSES) {
        float a = b2[t];
        #pragma unroll 4
        for (int k = 0; k < 128; ++k) a += qv[k] * w2[k * N_CLASSES + t];
        lg[t] = a;
    }
    __syncthreads();
    if (t < N_CLASSES) {
        float m = -INFINITY;
        #pragma unroll
        for (int j = 0; j < N_CLASSES; ++j) m = fmaxf(m, lg[j]);
        float sum = 0.f;
        #pragma unroll
        for (int j = 0; j < N_CLASSES; ++j) sum += __expf(lg[j] - m);
        out[(size_t)g * N_CLASSES + t] = lg[t] - m - __logf(sum);
    }
}

// ---------- launch ----------
static inline size_t align256(size_t x) { return (x + 255) & ~(size_t)255; }

extern "C" void kernel_launch(void* const* d_in, const int* in_sizes, int n_in,
                              void* d_out, int out_size, void* d_ws, size_t ws_size,
                              hipStream_t stream) {
    const float* x        = (const float*)d_in[0];
    const int*   ei       = (const int*)d_in[1];
    const int*   batch    = (const int*)d_in[2];
    const float* conv1_wl = (const float*)d_in[4];
    const float* conv1_wr = (const float*)d_in[5];
    const float* conv1_b  = (const float*)d_in[6];
    const float* convs_wl = (const float*)d_in[7];
    const float* convs_wr = (const float*)d_in[8];
    const float* convs_b  = (const float*)d_in[9];
    const float* gate_w   = (const float*)d_in[10];
    const float* gate_b   = (const float*)d_in[11];
    const float* lin1_w   = (const float*)d_in[12];
    const float* lin1_b   = (const float*)d_in[13];
    const float* lin2_w   = (const float*)d_in[14];
    const float* lin2_b   = (const float*)d_in[15];
    float* out = (float*)d_out;

    const int* src = ei;
    const int* dst = ei + N_EDGES;

    char* w = (char*)d_ws;
    size_t off = 0;
    unsigned short* h    = (unsigned short*)(w + off); off += align256((size_t)N_PAD * FEAT * 2);
    unsigned short* agg  = (unsigned short*)(w + off); off += align256((size_t)N_PAD * FEAT * 2);
    unsigned short* bkt  = (unsigned short*)(w + off); off += align256((size_t)N_NODES * BCAP * 2);
    unsigned short* wt   = (unsigned short*)(w + off); off += align256((size_t)3 * FEAT * K2 * 2);
    int*   i_cnt  = (int*)(w + off);   off += align256((size_t)N_NODES * 4);
    float* f_gate = (float*)(w + off); off += align256((size_t)N_NODES * 4);
    int*   i_goff = (int*)(w + off);   off += align256((size_t)(N_GRAPHS + 1) * 4);

    hipMemsetAsync(i_cnt, 0, (size_t)N_NODES * 4, stream);

    fill_bucket<<<12500, 256, 0, stream>>>(src, dst, i_cnt, bkt);
    setup_kernel<<<6250 + 384 + 3, 256, 0, stream>>>(
        x, h, conv1_wl, conv1_wr, convs_wl, convs_wr, wt, batch, i_goff);

    const int AB = (N_NODES + 3) / 4;   // 12500
    const int GB = N_PAD / 128;         // 391

    aggregate_bf16<<<AB, 256, 0, stream>>>(h, i_cnt, bkt, agg);
    gemm_mfma<<<GB, 256, 0, stream>>>(agg, h, wt, conv1_b);
    aggregate_bf16<<<AB, 256, 0, stream>>>(h, i_cnt, bkt, agg);
    gemm_mfma<<<GB, 256, 0, stream>>>(agg, h, wt + FEAT * K2, convs_b);
    aggregate_bf16<<<AB, 256, 0, stream>>>(h, i_cnt, bkt, agg);
    gemm_mfma<<<GB, 256, 0, stream>>>(agg, h, wt + 2 * FEAT * K2, convs_b + FEAT);

    pool_head<<<N_GRAPHS, 128, 0, stream>>>(h, gate_w, gate_b, i_goff, f_gate,
                                            lin1_w, lin1_b, lin2_w, lin2_b, out);
}

// Round 9
// 354.193 us; speedup vs baseline: 1.0852x; 1.0378x over previous
//
#include <hip/hip_runtime.h>
#include <math.h>

#define N_NODES 50000
#define N_PAD   50048
#define N_EDGES 800000
#define FEAT 128
#define K2 256
#define N_GRAPHS 512
#define N_CLASSES 10
#define BCAP 64          // bucket capacity (deg ~ Poisson(16); P(>64) ~ 0)
#define RANGE_SZ 12500   // 50000 / 4 dst ranges (1.6 MB ushort slice per range)

typedef __attribute__((ext_vector_type(8))) short short8;
typedef __attribute__((ext_vector_type(4))) float floatx4;

// ---------- bf16 helpers ----------
__device__ __forceinline__ float bflo(unsigned u) { return __uint_as_float(u << 16); }
__device__ __forceinline__ float bfhi(unsigned u) { return __uint_as_float(u & 0xffff0000u); }
__device__ __forceinline__ unsigned short f2bf(float f) {
    unsigned u = __float_as_uint(f);
    u = (u + 0x7fffu + ((u >> 16) & 1u)) >> 16;   // RNE
    return (unsigned short)u;
}
__device__ __forceinline__ unsigned pack2(float a, float b) {
    return (unsigned)f2bf(a) | ((unsigned)f2bf(b) << 16);
}
// monotone float->uint key; encoded 0 is below every real value's key
__device__ __forceinline__ unsigned fkey(float f) {
    unsigned b = __float_as_uint(f);
    return (b & 0x80000000u) ? ~b : (b | 0x80000000u);
}
__device__ __forceinline__ float fdecode(unsigned k) {
    unsigned b = (k & 0x80000000u) ? (k ^ 0x80000000u) : ~k;
    return __uint_as_float(b);
}

// ---------- bucket fill: one edge per thread, dst-range partitioned ----------
__global__ __launch_bounds__(256) void fill_bucket(
    const int* __restrict__ src, const int* __restrict__ dst,
    int* __restrict__ cnt, unsigned short* __restrict__ bucket) {
    int range = blockIdx.x & 3;
    int chunk = blockIdx.x >> 2;            // 0..3124
    int e = chunk * 256 + threadIdx.x;      // one edge per thread
    int lo = range * RANGE_SZ;
    int d = dst[e];
    if (d >= lo && d < lo + RANGE_SZ) {
        int p = atomicAdd(&cnt[d], 1);
        if (p < BCAP) bucket[(size_t)d * BCAP + p] = (unsigned short)src[e];
    }
}

// ---------- setup: x->bf16 | weight transpose+concat | goffs ----------
__global__ __launch_bounds__(256) void setup_kernel(
    const float* __restrict__ x, unsigned short* __restrict__ h,
    const float* __restrict__ wl1, const float* __restrict__ wr1,
    const float* __restrict__ wl23, const float* __restrict__ wr23,
    unsigned short* __restrict__ wt,
    const int* __restrict__ batch, int* __restrict__ goffs) {
    int b = blockIdx.x;
    if (b < 6250) {
        int idx = b * 256 + threadIdx.x;   // n*32 + f4
        if (idx < N_NODES * 32) {
            int n = idx >> 5, f4 = idx & 31;
            float4 v = ((const float4*)(x + (size_t)n * FEAT))[f4];
            uint2 o = make_uint2(pack2(v.x, v.y), pack2(v.z, v.w));
            *(uint2*)(h + (size_t)n * FEAT + f4 * 4) = o;
        }
    } else if (b < 6250 + 384) {
        int idx = (b - 6250) * 256 + threadIdx.x;  // 0..98303
        int layer = idx >> 15;
        int r = idx & 32767;
        int n = r >> 8, k = r & 255;
        const float* wl = (layer == 0) ? wl1 : wl23 + (size_t)(layer - 1) * FEAT * FEAT;
        const float* wr = (layer == 0) ? wr1 : wr23 + (size_t)(layer - 1) * FEAT * FEAT;
        float v = (k < FEAT) ? wl[k * FEAT + n] : wr[(k - FEAT) * FEAT + n];
        wt[idx] = f2bf(v);
    } else {
        int g = (b - 6250 - 384) * 256 + threadIdx.x;
        if (g > N_GRAPHS) return;
        int lo = 0, hi = N_NODES;
        while (lo < hi) {
            int mid = (lo + hi) >> 1;
            if (batch[mid] < g) lo = mid + 1; else hi = mid;
        }
        goffs[g] = lo;
    }
}

// ---------- aggregation: wave = node; 16-lane groups, dwordx4 gathers ----------
__device__ __forceinline__ void acc8(float* acc, uint4 u) {
    acc[0] += bflo(u.x); acc[1] += bfhi(u.x);
    acc[2] += bflo(u.y); acc[3] += bfhi(u.y);
    acc[4] += bflo(u.z); acc[5] += bfhi(u.z);
    acc[6] += bflo(u.w); acc[7] += bfhi(u.w);
}

__global__ __launch_bounds__(256) void aggregate_bf16(
    const unsigned short* __restrict__ h, const int* __restrict__ cnt,
    const unsigned short* __restrict__ bucket, unsigned short* __restrict__ agg) {
    int n = blockIdx.x * 4 + (threadIdx.x >> 6);
    if (n >= N_NODES) return;
    int lane = threadIdx.x & 63;
    int g = lane >> 4;        // edge slot within quad
    int l16 = lane & 15;      // 16 lanes x 16 B = 256 B row
    int deg = cnt[n];
    int c = min(deg, BCAP);
    int nq = c >> 2;
    int rem = c & 3;
    const unsigned short* cp = bucket + (size_t)n * BCAP;

    float acc[8];
    #pragma unroll
    for (int i = 0; i < 8; ++i) acc[i] = 0.f;

    int i = 0;
    for (; i + 4 <= nq; i += 4) {
        int s0 = cp[i * 4 + g];
        int s1 = cp[i * 4 + 4 + g];
        int s2 = cp[i * 4 + 8 + g];
        int s3 = cp[i * 4 + 12 + g];
        uint4 u0 = *(const uint4*)(h + (size_t)s0 * FEAT + l16 * 8);
        uint4 u1 = *(const uint4*)(h + (size_t)s1 * FEAT + l16 * 8);
        uint4 u2 = *(const uint4*)(h + (size_t)s2 * FEAT + l16 * 8);
        uint4 u3 = *(const uint4*)(h + (size_t)s3 * FEAT + l16 * 8);
        acc8(acc, u0); acc8(acc, u1); acc8(acc, u2); acc8(acc, u3);
    }
    if (i + 2 <= nq) {
        int s0 = cp[i * 4 + g];
        int s1 = cp[i * 4 + 4 + g];
        uint4 u0 = *(const uint4*)(h + (size_t)s0 * FEAT + l16 * 8);
        uint4 u1 = *(const uint4*)(h + (size_t)s1 * FEAT + l16 * 8);
        acc8(acc, u0); acc8(acc, u1);
        i += 2;
    }
    if (i < nq) {
        int s0 = cp[i * 4 + g];
        uint4 u0 = *(const uint4*)(h + (size_t)s0 * FEAT + l16 * 8);
        acc8(acc, u0);
    }
    if (g < rem) {
        int s0 = cp[nq * 4 + g];
        uint4 u0 = *(const uint4*)(h + (size_t)s0 * FEAT + l16 * 8);
        acc8(acc, u0);
    }
    #pragma unroll
    for (int j = 0; j < 8; ++j) {
        acc[j] += __shfl_xor(acc[j], 16);
        acc[j] += __shfl_xor(acc[j], 32);
    }
    if (g == 0) {
        float inv = 1.0f / fmaxf((float)deg, 1.0f);
        uint4 o;
        o.x = pack2(acc[0] * inv, acc[1] * inv);
        o.y = pack2(acc[2] * inv, acc[3] * inv);
        o.z = pack2(acc[4] * inv, acc[5] * inv);
        o.w = pack2(acc[6] * inv, acc[7] * inv);
        *(uint4*)(agg + (size_t)n * FEAT + l16 * 8) = o;
    }
}

// ---------- MFMA GEMM: h = relu([agg|h] @ Wt^T + b), in place ----------
// Optional fused gate epilogue (layer 3): gate[m] = dot(h_new[m], gate_w)
// computed from the fp32 accumulators; per-graph running max via encoded
// atomicMax.  gate_b is omitted — it cancels in the segment softmax.
__global__ __launch_bounds__(256) void gemm_mfma(
    const unsigned short* __restrict__ agg, unsigned short* __restrict__ h,
    const unsigned short* __restrict__ Wt, const float* __restrict__ bias,
    const float* __restrict__ gate_w, float* __restrict__ gate,
    unsigned* __restrict__ gmax, const int* __restrict__ batch) {
    int wave = threadIdx.x >> 6, lane = threadIdx.x & 63;
    int q = lane >> 4, l16 = lane & 15;
    int row0 = blockIdx.x * 128 + wave * 32;
    const unsigned short* pa0 = agg + (size_t)(row0 + l16) * FEAT + q * 8;
    const unsigned short* pa1 = pa0 + 16 * FEAT;
    const unsigned short* ph0 = h + (size_t)(row0 + l16) * FEAT + q * 8;
    const unsigned short* ph1 = ph0 + 16 * FEAT;
    const unsigned short* pb  = Wt + (size_t)l16 * K2 + q * 8;

    short8 a0[8], a1[8];
    #pragma unroll
    for (int ks = 0; ks < 4; ++ks) {
        a0[ks] = *(const short8*)(pa0 + ks * 32);
        a1[ks] = *(const short8*)(pa1 + ks * 32);
        a0[4 + ks] = *(const short8*)(ph0 + ks * 32);
        a1[4 + ks] = *(const short8*)(ph1 + ks * 32);
    }
    __syncthreads();

    floatx4 acc[2][8];
    #pragma unroll
    for (int i = 0; i < 2; ++i)
        #pragma unroll
        for (int j = 0; j < 8; ++j) acc[i][j] = (floatx4){0.f, 0.f, 0.f, 0.f};

    #pragma unroll
    for (int ks = 0; ks < 8; ++ks) {
        #pragma unroll
        for (int nb = 0; nb < 8; ++nb) {
            short8 b = *(const short8*)(pb + (size_t)nb * 16 * K2 + ks * 32);
            acc[0][nb] = __builtin_amdgcn_mfma_f32_16x16x32_bf16(a0[ks], b, acc[0][nb], 0, 0, 0);
            acc[1][nb] = __builtin_amdgcn_mfma_f32_16x16x32_bf16(a1[ks], b, acc[1][nb], 0, 0, 0);
        }
    }

    float bv[8], gwv[8];
    #pragma unroll
    for (int nb = 0; nb < 8; ++nb) bv[nb] = bias[nb * 16 + l16];
    if (gate_w) {
        #pragma unroll
        for (int nb = 0; nb < 8; ++nb) gwv[nb] = gate_w[nb * 16 + l16];
    }

    #pragma unroll
    for (int band = 0; band < 2; ++band) {
        #pragma unroll
        for (int r = 0; r < 4; ++r) {
            int m = row0 + band * 16 + q * 4 + r;
            float gsum = 0.f;
            #pragma unroll
            for (int nb = 0; nb < 8; ++nb) {
                float v = fmaxf(acc[band][nb][r] + bv[nb], 0.f);
                if (m < N_NODES) h[(size_t)m * FEAT + nb * 16 + l16] = f2bf(v);
                gsum += v * gwv[nb];
            }
            if (gate_w) {
                gsum += __shfl_xor(gsum, 1);
                gsum += __shfl_xor(gsum, 2);
                gsum += __shfl_xor(gsum, 4);
                gsum += __shfl_xor(gsum, 8);
                if (l16 == 0 && m < N_NODES) {
                    gate[m] = gsum;
                    atomicMax(&gmax[batch[m]], fkey(gsum));
                }
            }
        }
    }
}

// ---------- pooling + head: one block (256 thr) per graph, single h pass ----------
__global__ __launch_bounds__(256) void pool_head(
    const unsigned short* __restrict__ h, const float* __restrict__ gate,
    const unsigned* __restrict__ gmax, const int* __restrict__ goffs,
    const float* __restrict__ w1, const float* __restrict__ b1,
    const float* __restrict__ w2, const float* __restrict__ b2,
    float* __restrict__ out) {
    __shared__ float sred[4];
    __shared__ float facc[4][128];
    __shared__ float pv[128], qv[128], lg[N_CLASSES];
    int g = blockIdx.x;
    int s = goffs[g], e = goffs[g + 1];
    int t = threadIdx.x;
    int wave = t >> 6, lane = t & 63;

    if (s < e) {
        float m = fdecode(gmax[g]);
        // denominator
        float d = 0.f;
        for (int n = s + t; n < e; n += 256) d += __expf(gate[n] - m);
        #pragma unroll
        for (int off = 32; off; off >>= 1) d += __shfl_xor(d, off);
        if (lane == 0) sred[wave] = d;
        __syncthreads();
        float den = sred[0] + sred[1] + sred[2] + sred[3];
        // single pass weighted feature sum: wave w covers nodes s+w, s+w+4, ...
        float acc0 = 0.f, acc1 = 0.f;
        for (int n = s + wave; n < e; n += 4) {
            float gn = __expf(gate[n] - m);
            unsigned u = *(const unsigned*)(h + (size_t)n * FEAT + lane * 2);
            acc0 += gn * bflo(u);
            acc1 += gn * bfhi(u);
        }
        facc[wave][lane * 2]     = acc0;
        facc[wave][lane * 2 + 1] = acc1;
        __syncthreads();
        if (t < 128) pv[t] = (facc[0][t] + facc[1][t] + facc[2][t] + facc[3][t]) / den;
    } else {
        if (t < 128) pv[t] = 0.f;
    }
    __syncthreads();

    if (t < 128) {
        float acc = b1[t];
        #pragma unroll 4
        for (int k = 0; k < 128; ++k) acc += pv[k] * w1[k * FEAT + t];
        qv[t] = fmaxf(acc, 0.f);
    }
    __syncthreads();
    if (t < N_CLASSES) {
        float a = b2[t];
        #pragma unroll 4
        for (int k = 0; k < 128; ++k) a += qv[k] * w2[k * N_CLASSES + t];
        lg[t] = a;
    }
    __syncthreads();
    if (t < N_CLASSES) {
        float m = -INFINITY;
        #pragma unroll
        for (int j = 0; j < N_CLASSES; ++j) m = fmaxf(m, lg[j]);
        float sum = 0.f;
        #pragma unroll
        for (int j = 0; j < N_CLASSES; ++j) sum += __expf(lg[j] - m);
        out[(size_t)g * N_CLASSES + t] = lg[t] - m - __logf(sum);
    }
}

// ---------- launch ----------
static inline size_t align256(size_t x) { return (x + 255) & ~(size_t)255; }

extern "C" void kernel_launch(void* const* d_in, const int* in_sizes, int n_in,
                              void* d_out, int out_size, void* d_ws, size_t ws_size,
                              hipStream_t stream) {
    const float* x        = (const float*)d_in[0];
    const int*   ei       = (const int*)d_in[1];
    const int*   batch    = (const int*)d_in[2];
    const float* conv1_wl = (const float*)d_in[4];
    const float* conv1_wr = (const float*)d_in[5];
    const float* conv1_b  = (const float*)d_in[6];
    const float* convs_wl = (const float*)d_in[7];
    const float* convs_wr = (const float*)d_in[8];
    const float* convs_b  = (const float*)d_in[9];
    const float* gate_w   = (const float*)d_in[10];
    const float* lin1_w   = (const float*)d_in[12];
    const float* lin1_b   = (const float*)d_in[13];
    const float* lin2_w   = (const float*)d_in[14];
    const float* lin2_b   = (const float*)d_in[15];
    float* out = (float*)d_out;

    const int* src = ei;
    const int* dst = ei + N_EDGES;

    char* w = (char*)d_ws;
    size_t off = 0;
    unsigned short* h    = (unsigned short*)(w + off); off += align256((size_t)N_PAD * FEAT * 2);
    unsigned short* agg  = (unsigned short*)(w + off); off += align256((size_t)N_PAD * FEAT * 2);
    unsigned short* bkt  = (unsigned short*)(w + off); off += align256((size_t)N_NODES * BCAP * 2);
    unsigned short* wt   = (unsigned short*)(w + off); off += align256((size_t)3 * FEAT * K2 * 2);
    float* f_gate = (float*)(w + off); off += align256((size_t)N_NODES * 4);
    int*   i_goff = (int*)(w + off);   off += align256((size_t)(N_GRAPHS + 1) * 4);
    // zero region: cnt + gmax contiguous
    char* zbase = w + off;
    int*      i_cnt  = (int*)(w + off);      off += align256((size_t)N_NODES * 4);
    unsigned* u_gmax = (unsigned*)(w + off); off += align256((size_t)N_GRAPHS * 4);
    size_t zbytes = (size_t)((w + off) - zbase);

    hipMemsetAsync(zbase, 0, zbytes, stream);

    fill_bucket<<<12500, 256, 0, stream>>>(src, dst, i_cnt, bkt);
    setup_kernel<<<6250 + 384 + 3, 256, 0, stream>>>(
        x, h, conv1_wl, conv1_wr, convs_wl, convs_wr, wt, batch, i_goff);

    const int AB = (N_NODES + 3) / 4;   // 12500
    const int GB = N_PAD / 128;         // 391

    aggregate_bf16<<<AB, 256, 0, stream>>>(h, i_cnt, bkt, agg);
    gemm_mfma<<<GB, 256, 0, stream>>>(agg, h, wt, conv1_b,
                                      nullptr, nullptr, nullptr, nullptr);
    aggregate_bf16<<<AB, 256, 0, stream>>>(h, i_cnt, bkt, agg);
    gemm_mfma<<<GB, 256, 0, stream>>>(agg, h, wt + FEAT * K2, convs_b,
                                      nullptr, nullptr, nullptr, nullptr);
    aggregate_bf16<<<AB, 256, 0, stream>>>(h, i_cnt, bkt, agg);
    gemm_mfma<<<GB, 256, 0, stream>>>(agg, h, wt + 2 * FEAT * K2, convs_b + FEAT,
                                      gate_w, f_gate, u_gmax, batch);

    pool_head<<<N_GRAPHS, 256, 0, stream>>>(h, f_gate, u_gmax, i_goff,
                                            lin1_w, lin1_b, lin2_w, lin2_b, out);
}